// Round 6
// baseline (417.468 us; speedup 1.0000x reference)
//
#include <hip/hip_runtime.h>
#include <hip/hip_bf16.h>

#define C_  64
#define C3_ 192
#define T_  10
#define H_  128
#define W_  128
#define HW_ 16384        // H_*W_
#define THW_ 163840      // T_*HW_
#define NH_ 8
#define C2_ 24
#define TG_ 80           // t * SHUFFLE_G

typedef __hip_bfloat16 bf16;
typedef __attribute__((ext_vector_type(8))) short bf16x8;
typedef __attribute__((ext_vector_type(4))) float f32x4;

__device__ __forceinline__ float bf2f(bf16 v) { return __bfloat162float(v); }

__device__ __forceinline__ ushort f2bf_s(float f) {
  bf16 h = __float2bfloat16(f);
  union { bf16 b; ushort s; } u; u.b = h; return u.s;
}

__device__ __forceinline__ void unpack8(uint4 u, float* f) {
  f[0] = __uint_as_float(u.x << 16); f[1] = __uint_as_float(u.x & 0xffff0000u);
  f[2] = __uint_as_float(u.y << 16); f[3] = __uint_as_float(u.y & 0xffff0000u);
  f[4] = __uint_as_float(u.z << 16); f[5] = __uint_as_float(u.z & 0xffff0000u);
  f[6] = __uint_as_float(u.w << 16); f[7] = __uint_as_float(u.w & 0xffff0000u);
}

__device__ __forceinline__ ushort4 pack4(f32x4 a) {
  ushort4 p;
  p.x = f2bf_s(a[0]); p.y = f2bf_s(a[1]); p.z = f2bf_s(a[2]); p.w = f2bf_s(a[3]);
  return p;
}

// ================ K1 (MFMA, direct-gather, no LDS): y1 = W1 @ x ================
// A-frag: lane gathers x[k0..k0+8) at its col (8 scalar f32, 64B-coalesced per 16 lanes)
__global__ __launch_bounds__(256) void k1_mfma(
    const float* __restrict__ x, const float* __restrict__ W1,
    bf16* __restrict__ y1) {
  const int tid = threadIdx.x;
  const int n0 = blockIdx.x * 256;
  const int mh = blockIdx.y;
  const int lane = tid & 63, wv = tid >> 6;
  const int lr = lane & 15, lg = lane >> 4;

  // B fragments: W1 rows (o-channels), 6 m-tiles x 2 k-chunks
  bf16x8 wf[6][2];
#pragma unroll
  for (int mt = 0; mt < 6; ++mt)
#pragma unroll
    for (int c = 0; c < 2; ++c) {
      const int row = mh * 96 + mt * 16 + lr;
      const int k0 = c * 32 + lg * 8;
      const float* wp = W1 + row * 64 + k0;
      float4 a0 = *reinterpret_cast<const float4*>(wp);
      float4 a1 = *reinterpret_cast<const float4*>(wp + 4);
      bf16x8 f;
      f[0]=f2bf_s(a0.x); f[1]=f2bf_s(a0.y); f[2]=f2bf_s(a0.z); f[3]=f2bf_s(a0.w);
      f[4]=f2bf_s(a1.x); f[5]=f2bf_s(a1.y); f[6]=f2bf_s(a1.z); f[7]=f2bf_s(a1.w);
      wf[mt][c] = f;
    }

#pragma unroll
  for (int nt = 0; nt < 4; ++nt) {
    const int col = wv * 64 + nt * 16 + lr;
    const float* xc = x + n0 + col + (size_t)(lg * 8) * THW_;
    bf16x8 xa[2];
#pragma unroll
    for (int c = 0; c < 2; ++c) {
      float v[8];
#pragma unroll
      for (int e = 0; e < 8; ++e) v[e] = xc[(size_t)(c * 32 + e) * THW_];
      bf16x8 f;
#pragma unroll
      for (int e = 0; e < 8; ++e) f[e] = f2bf_s(v[e]);
      xa[c] = f;
    }
    f32x4 acc[6];
#pragma unroll
    for (int mt = 0; mt < 6; ++mt) acc[mt] = (f32x4){0.f, 0.f, 0.f, 0.f};
#pragma unroll
    for (int c = 0; c < 2; ++c)
#pragma unroll
      for (int mt = 0; mt < 6; ++mt)
        acc[mt] = __builtin_amdgcn_mfma_f32_16x16x32_bf16(xa[c], wf[mt][c], acc[mt], 0, 0, 0);
    const int nb = n0 + wv * 64 + nt * 16 + lg * 4;
#pragma unroll
    for (int mt = 0; mt < 6; ++mt) {
      const int o = mh * 96 + mt * 16 + lr;
      *reinterpret_cast<ushort4*>(y1 + (size_t)o * THW_ + nb) = pack4(acc[mt]);
    }
  }
}

// ================ K2: depthwise 3x3, 32x128 tile, conflict-free — unchanged ================
__global__ __launch_bounds__(256) void k2_dw(
    const bf16* __restrict__ y1, const float* __restrict__ Wdw,
    bf16* __restrict__ y2) {
  __shared__ float tile[34][132];
  const int tid = threadIdx.x;
  const int blk = blockIdx.x;
  const int hs = (blk & 3) * 32;
  const int rest = blk >> 2;
  const int t = rest % T_;
  const int o = rest / T_;
  const bf16* src = y1 + ((size_t)o * T_ + t) * HW_;

  if (tid < 68) {
    const int r = tid >> 1, side = tid & 1;
    tile[r][side ? 129 : 0] = 0.f;
  }
  {
    const int rr = tid >> 5, c4 = (tid & 31) * 4;
#pragma unroll
    for (int p = 0; p < 5; ++p) {
      const int r = p * 8 + rr;
      if (r < 34) {
        const int hh = hs - 1 + r;
        float e0 = 0.f, e1 = 0.f, e2 = 0.f, e3 = 0.f;
        if (hh >= 0 && hh < H_) {
          uint2 raw = *reinterpret_cast<const uint2*>(src + hh * W_ + c4);
          e0 = __uint_as_float(raw.x << 16);
          e1 = __uint_as_float(raw.x & 0xffff0000u);
          e2 = __uint_as_float(raw.y << 16);
          e3 = __uint_as_float(raw.y & 0xffff0000u);
        }
        tile[r][1 + c4]     = e0;
        tile[r][1 + c4 + 1] = e1;
        tile[r][1 + c4 + 2] = e2;
        tile[r][1 + c4 + 3] = e3;
      }
    }
  }
  __syncthreads();

  float kk[9];
#pragma unroll
  for (int i = 0; i < 9; ++i) kk[i] = Wdw[o * 9 + i];

  bf16* dst = y2 + ((size_t)o * T_ + t) * HW_;
  const int w = tid & 127;
  const int r0 = (tid >> 7) * 16;

  float a[3][3];
#pragma unroll
  for (int ky = 0; ky < 3; ++ky)
#pragma unroll
    for (int kx = 0; kx < 3; ++kx) a[ky][kx] = tile[r0 + ky][w + kx];

#pragma unroll
  for (int q = 0; q < 16; ++q) {
    float acc = 0.f;
#pragma unroll
    for (int ky = 0; ky < 3; ++ky)
#pragma unroll
      for (int kx = 0; kx < 3; ++kx)
        acc = fmaf(kk[ky * 3 + kx], a[ky][kx], acc);
    dst[(hs + r0 + q) * W_ + w] = __float2bfloat16(acc);
    if (q < 15) {
#pragma unroll
      for (int kx = 0; kx < 3; ++kx) {
        a[0][kx] = a[1][kx];
        a[1][kx] = a[2][kx];
        a[2][kx] = tile[r0 + q + 3][w + kx];
      }
    }
  }
}

// ================ K3 (MFMA, direct-gather): z = W_lin @ shuffled(y2) + b ================
__global__ __launch_bounds__(256) void k3_mfma(
    const bf16* __restrict__ y2, const float* __restrict__ W_lin,
    const float* __restrict__ b_lin, bf16* __restrict__ z) {
  const int tid = threadIdx.x;
  const int s0 = blockIdx.x * 256;
  const int c2 = blockIdx.y;
  const int lane = tid & 63, wv = tid >> 6;
  const int lr = lane & 15, lg = lane >> 4;
  const ushort* y2u = reinterpret_cast<const ushort*>(y2);

  bf16x8 wf[5][3];
#pragma unroll
  for (int mt = 0; mt < 5; ++mt)
#pragma unroll
    for (int c = 0; c < 3; ++c) {
      const int row = mt * 16 + lr;
      const int k0 = c * 32 + lg * 8;
      bf16x8 f;
      if (k0 < 80) {
        const float* wp = W_lin + row * 80 + k0;
        float4 a0 = *reinterpret_cast<const float4*>(wp);
        float4 a1 = *reinterpret_cast<const float4*>(wp + 4);
        f[0]=f2bf_s(a0.x); f[1]=f2bf_s(a0.y); f[2]=f2bf_s(a0.z); f[3]=f2bf_s(a0.w);
        f[4]=f2bf_s(a1.x); f[5]=f2bf_s(a1.y); f[6]=f2bf_s(a1.z); f[7]=f2bf_s(a1.w);
      } else {
        f = (bf16x8){0,0,0,0,0,0,0,0};
      }
      wf[mt][c] = f;
    }
  float bias[5];
#pragma unroll
  for (int mt = 0; mt < 5; ++mt) bias[mt] = b_lin[mt * 16 + lr];

#pragma unroll
  for (int nt = 0; nt < 4; ++nt) {
    const int col = wv * 64 + nt * 16 + lr;
    const int sidx = s0 + col;
    bf16x8 xa[3];
#pragma unroll
    for (int c = 0; c < 3; ++c) {
      bf16x8 f = (bf16x8){0,0,0,0,0,0,0,0};
#pragma unroll
      for (int e = 0; e < 8; ++e) {
        const int k = c * 32 + lg * 8 + e;        // i = c1*10 + tt, k<80 valid
        if (k < 80) {
          const int c1 = (k * 205) >> 11;
          const int tt = k - c1 * 10;
          const int row = c1 * 240 + c2 * 10 + tt;   // (c1*C2+c2)*T + tt
          f[e] = (short)y2u[(size_t)row * HW_ + sidx];
        }
      }
      xa[c] = f;
    }
    f32x4 acc[5];
#pragma unroll
    for (int mt = 0; mt < 5; ++mt)
      acc[mt] = (f32x4){bias[mt], bias[mt], bias[mt], bias[mt]};
#pragma unroll
    for (int c = 0; c < 3; ++c)
#pragma unroll
      for (int mt = 0; mt < 5; ++mt)
        acc[mt] = __builtin_amdgcn_mfma_f32_16x16x32_bf16(xa[c], wf[mt][c], acc[mt], 0, 0, 0);
    const int sb = s0 + wv * 64 + nt * 16 + lg * 4;
#pragma unroll
    for (int mt = 0; mt < 5; ++mt) {
      const int u = c2 * TG_ + mt * 16 + lr;
      *reinterpret_cast<ushort4*>(z + (size_t)u * HW_ + sb) = pack4(acc[mt]);
    }
  }
}

// ================ K4: sum of squares for q,k rows — unchanged ================
__global__ __launch_bounds__(256) void k4_ssq(
    const bf16* __restrict__ z, float* __restrict__ ssq) {
  __shared__ float red[256];
  int u = blockIdx.x;
  const bf16* p = z + (size_t)u * HW_;
  float acc = 0.f;
  for (int it = 0; it < 8; ++it) {
    int s = it * 2048 + threadIdx.x * 8;
    uint4 raw = *reinterpret_cast<const uint4*>(p + s);
    float f[8]; unpack8(raw, f);
#pragma unroll
    for (int e = 0; e < 8; ++e) acc = fmaf(f[e], f[e], acc);
  }
  red[threadIdx.x] = acc;
  __syncthreads();
  for (int st = 128; st > 0; st >>= 1) {
    if (threadIdx.x < st) red[threadIdx.x] += red[threadIdx.x + st];
    __syncthreads();
  }
  if (threadIdx.x == 0) ssq[u] = red[0];
}

// ================ K5 (MFMA): Gpart[chunk] = partial QK^T over 512-s chunk — unchanged ================
__global__ __launch_bounds__(256) void k5_mfma(
    const bf16* __restrict__ z, float* __restrict__ Gpart) {
  __shared__ __align__(16) float gbuf[2][TG_ * TG_];   // 51.2 KiB
  const int chunk = blockIdx.x, h = blockIdx.y;
  const int tid = threadIdx.x;
  const int lane = tid & 63, wv = tid >> 6;
  const int lr = lane & 15, lg = lane >> 4;

  const bf16* qbase = z + (size_t)(h * TG_) * HW_;
  const bf16* kbase = z + (size_t)((8 + h) * TG_) * HW_;

  f32x4 acc[5][5];
#pragma unroll
  for (int a = 0; a < 5; ++a)
#pragma unroll
    for (int b2 = 0; b2 < 5; ++b2) acc[a][b2] = (f32x4){0.f, 0.f, 0.f, 0.f};

  const int s0 = chunk * 512 + wv * 128;
  for (int s = s0; s < s0 + 128; s += 32) {
    bf16x8 qa[5], kb[5];
#pragma unroll
    for (int a = 0; a < 5; ++a)
      qa[a] = *reinterpret_cast<const bf16x8*>(qbase + (size_t)(a * 16 + lr) * HW_ + s + lg * 8);
#pragma unroll
    for (int a = 0; a < 5; ++a)
      kb[a] = *reinterpret_cast<const bf16x8*>(kbase + (size_t)(a * 16 + lr) * HW_ + s + lg * 8);
#pragma unroll
    for (int a = 0; a < 5; ++a)
#pragma unroll
      for (int b2 = 0; b2 < 5; ++b2)
        acc[a][b2] = __builtin_amdgcn_mfma_f32_16x16x32_bf16(qa[a], kb[b2], acc[a][b2], 0, 0, 0);
  }

  if (wv == 1 || wv == 3) {
    float* dst = gbuf[wv >> 1];
#pragma unroll
    for (int a = 0; a < 5; ++a)
#pragma unroll
      for (int b2 = 0; b2 < 5; ++b2)
#pragma unroll
        for (int j = 0; j < 4; ++j)
          dst[(a * 16 + lg * 4 + j) * TG_ + b2 * 16 + lr] = acc[a][b2][j];
  }
  __syncthreads();
  if (wv == 0 || wv == 2) {
    const float* srcb = gbuf[wv >> 1];
#pragma unroll
    for (int a = 0; a < 5; ++a)
#pragma unroll
      for (int b2 = 0; b2 < 5; ++b2)
#pragma unroll
        for (int j = 0; j < 4; ++j)
          acc[a][b2][j] += srcb[(a * 16 + lg * 4 + j) * TG_ + b2 * 16 + lr];
  }
  __syncthreads();
  if (wv == 2) {
#pragma unroll
    for (int a = 0; a < 5; ++a)
#pragma unroll
      for (int b2 = 0; b2 < 5; ++b2)
#pragma unroll
        for (int j = 0; j < 4; ++j)
          gbuf[0][(a * 16 + lg * 4 + j) * TG_ + b2 * 16 + lr] = acc[a][b2][j];
  }
  __syncthreads();
  if (wv == 0) {
    float* gp = Gpart + ((size_t)chunk * 8 + h) * TG_ * TG_;
#pragma unroll
    for (int a = 0; a < 5; ++a)
#pragma unroll
      for (int b2 = 0; b2 < 5; ++b2)
#pragma unroll
        for (int j = 0; j < 4; ++j) {
          const int i = a * 16 + lg * 4 + j, jj = b2 * 16 + lr;
          gp[i * TG_ + jj] = acc[a][b2][j] + gbuf[0][i * TG_ + jj];
        }
  }
}

// ================ K6: softmax — unchanged ================
__global__ __launch_bounds__(128) void k6_softmax(
    const float* __restrict__ Gpart, const float* __restrict__ ssq,
    const float* __restrict__ temp, float* __restrict__ attn) {
  __shared__ float red[128];
  __shared__ float smax, ssum;
  int h = blockIdx.x / TG_, i = blockIdx.x % TG_;
  int j = threadIdx.x;
  float logit = -1e30f;
  if (j < TG_) {
    float g = 0.f;
    for (int c = 0; c < 32; ++c)
      g += Gpart[(((size_t)c * 8 + h) * TG_ + i) * TG_ + j];
    float nq = ssq[h * TG_ + i];
    float nk = ssq[(8 + h) * TG_ + j];
    float sq = 1.f / fmaxf(sqrtf(nq), 1e-12f);
    float sk = 1.f / fmaxf(sqrtf(nk), 1e-12f);
    logit = g * sq * sk * temp[h];
  }
  red[j] = logit;
  __syncthreads();
  if (j == 0) {
    float m = -1e30f;
    for (int x2 = 0; x2 < TG_; ++x2) m = fmaxf(m, red[x2]);
    smax = m;
  }
  __syncthreads();
  float e = (j < TG_) ? expf(logit - smax) : 0.f;
  red[j] = e;
  __syncthreads();
  if (j == 0) {
    float s = 0.f;
    for (int x2 = 0; x2 < TG_; ++x2) s += red[x2];
    ssum = s;
  }
  __syncthreads();
  if (j < TG_) attn[((size_t)h * TG_ + i) * TG_ + j] = e / ssum;
}

// ================ K7a (MFMA, direct-gather): att_out = attn @ v ================
__global__ __launch_bounds__(256) void k7a_mfma(
    const bf16* __restrict__ z, const float* __restrict__ attn,
    bf16* __restrict__ att_out) {
  const int tid = threadIdx.x;
  const int s0 = blockIdx.x * 256;
  const int h = blockIdx.y;
  const int voff = (16 + h) * TG_;
  const int lane = tid & 63, wv = tid >> 6;
  const int lr = lane & 15, lg = lane >> 4;
  const ushort* zu = reinterpret_cast<const ushort*>(z);

  bf16x8 wf[5][3];
#pragma unroll
  for (int mt = 0; mt < 5; ++mt)
#pragma unroll
    for (int c = 0; c < 3; ++c) {
      const int row = mt * 16 + lr;
      const int k0 = c * 32 + lg * 8;
      bf16x8 f;
      if (k0 < 80) {
        const float* ap = attn + ((size_t)h * TG_ + row) * TG_ + k0;
        float4 a0 = *reinterpret_cast<const float4*>(ap);
        float4 a1 = *reinterpret_cast<const float4*>(ap + 4);
        f[0]=f2bf_s(a0.x); f[1]=f2bf_s(a0.y); f[2]=f2bf_s(a0.z); f[3]=f2bf_s(a0.w);
        f[4]=f2bf_s(a1.x); f[5]=f2bf_s(a1.y); f[6]=f2bf_s(a1.z); f[7]=f2bf_s(a1.w);
      } else {
        f = (bf16x8){0,0,0,0,0,0,0,0};
      }
      wf[mt][c] = f;
    }

#pragma unroll
  for (int nt = 0; nt < 4; ++nt) {
    const int col = wv * 64 + nt * 16 + lr;
    const int sidx = s0 + col;
    bf16x8 xa[3];
#pragma unroll
    for (int c = 0; c < 3; ++c) {
      bf16x8 f = (bf16x8){0,0,0,0,0,0,0,0};
#pragma unroll
      for (int e = 0; e < 8; ++e) {
        const int k = c * 32 + lg * 8 + e;
        if (k < 80)
          f[e] = (short)zu[(size_t)(voff + k) * HW_ + sidx];
      }
      xa[c] = f;
    }
    f32x4 acc[5];
#pragma unroll
    for (int mt = 0; mt < 5; ++mt) acc[mt] = (f32x4){0.f, 0.f, 0.f, 0.f};
#pragma unroll
    for (int c = 0; c < 3; ++c)
#pragma unroll
      for (int mt = 0; mt < 5; ++mt)
        acc[mt] = __builtin_amdgcn_mfma_f32_16x16x32_bf16(xa[c], wf[mt][c], acc[mt], 0, 0, 0);
    const int sb = s0 + wv * 64 + nt * 16 + lg * 4;
#pragma unroll
    for (int mt = 0; mt < 5; ++mt) {
      const int u = h * TG_ + mt * 16 + lr;
      *reinterpret_cast<ushort4*>(att_out + (size_t)u * HW_ + sb) = pack4(acc[mt]);
    }
  }
}

// ================ K7b (MFMA, direct-gather): out = W_out @ regroup(att_out), f32 out ================
__global__ __launch_bounds__(256) void k7b_mfma(
    const bf16* __restrict__ att_out, const float* __restrict__ W_out,
    float* __restrict__ out) {
  const int tid = threadIdx.x;
  const int n0 = blockIdx.x * 256;
  const int t = n0 >> 14;
  const int sb0 = n0 & (HW_ - 1);
  const int lane = tid & 63, wv = tid >> 6;
  const int lr = lane & 15, lg = lane >> 4;
  const ushort* au = reinterpret_cast<const ushort*>(att_out);

  bf16x8 wf[4][2];
#pragma unroll
  for (int mt = 0; mt < 4; ++mt)
#pragma unroll
    for (int c = 0; c < 2; ++c) {
      const int row = mt * 16 + lr;
      const int k0 = c * 32 + lg * 8;
      const float* wp = W_out + row * 64 + k0;
      float4 a0 = *reinterpret_cast<const float4*>(wp);
      float4 a1 = *reinterpret_cast<const float4*>(wp + 4);
      bf16x8 f;
      f[0]=f2bf_s(a0.x); f[1]=f2bf_s(a0.y); f[2]=f2bf_s(a0.z); f[3]=f2bf_s(a0.w);
      f[4]=f2bf_s(a1.x); f[5]=f2bf_s(a1.y); f[6]=f2bf_s(a1.z); f[7]=f2bf_s(a1.w);
      wf[mt][c] = f;
    }

#pragma unroll
  for (int nt = 0; nt < 4; ++nt) {
    const int col = wv * 64 + nt * 16 + lr;
    const int sidx = sb0 + col;
    bf16x8 xa[2];
#pragma unroll
    for (int c = 0; c < 2; ++c) {
      bf16x8 f;
#pragma unroll
      for (int e = 0; e < 8; ++e) {
        const int k = c * 32 + lg * 8 + e;
        const int row = (k >> 3) * TG_ + (k & 7) * T_ + t;   // head regroup
        f[e] = (short)au[(size_t)row * HW_ + sidx];
      }
      xa[c] = f;
    }
    f32x4 acc[4];
#pragma unroll
    for (int mt = 0; mt < 4; ++mt) acc[mt] = (f32x4){0.f, 0.f, 0.f, 0.f};
#pragma unroll
    for (int c = 0; c < 2; ++c)
#pragma unroll
      for (int mt = 0; mt < 4; ++mt)
        acc[mt] = __builtin_amdgcn_mfma_f32_16x16x32_bf16(xa[c], wf[mt][c], acc[mt], 0, 0, 0);
    const int nb = n0 + wv * 64 + nt * 16 + lg * 4;
#pragma unroll
    for (int mt = 0; mt < 4; ++mt) {
      const int o = mt * 16 + lr;
      *reinterpret_cast<float4*>(out + (size_t)o * THW_ + nb) =
          (float4){acc[mt][0], acc[mt][1], acc[mt][2], acc[mt][3]};
    }
  }
}

extern "C" void kernel_launch(void* const* d_in, const int* in_sizes, int n_in,
                              void* d_out, int out_size, void* d_ws, size_t ws_size,
                              hipStream_t stream) {
  const float* x    = (const float*)d_in[0];
  const float* W1   = (const float*)d_in[1];
  const float* Wdw  = (const float*)d_in[2];
  const float* Wlin = (const float*)d_in[3];
  const float* blin = (const float*)d_in[4];
  const float* temp = (const float*)d_in[5];
  const float* Wout = (const float*)d_in[6];
  float* out = (float*)d_out;

  const size_t SLOT = (size_t)C3_ * THW_ * 2;   // 62,914,560 bytes
  char* ws = (char*)d_ws;
  bf16* slotA = (bf16*)ws;
  char* slotB = ws + SLOT;

  bf16* y1 = slotA;
  bf16* y2 = (bf16*)slotB;
  bf16* z  = slotA;
  float* Gpart   = (float*)slotB;                // 6,553,600 B
  float* attn    = (float*)(slotB + 6553600);    //   204,800 B
  float* ssq     = (float*)(slotB + 6758400);    //     5,120 B
  bf16*  att_out = (bf16*)(slotB + 6763520);     // 20,971,520 B

  for (int b = 0; b < 2; ++b) {
    const float* x_b = x + (size_t)b * C_ * THW_;
    float* out_b = out + (size_t)b * C_ * THW_;

    k1_mfma<<<dim3(THW_ / 256, 2), 256, 0, stream>>>(x_b, W1, y1);
    k2_dw<<<C3_ * T_ * 4, 256, 0, stream>>>(y1, Wdw, y2);
    k3_mfma<<<dim3(HW_ / 256, C2_), 256, 0, stream>>>(y2, Wlin, blin, z);
    k4_ssq<<<1280, 256, 0, stream>>>(z, ssq);
    k5_mfma<<<dim3(32, NH_), 256, 0, stream>>>(z, Gpart);
    k6_softmax<<<8 * TG_, 128, 0, stream>>>(Gpart, ssq, temp, attn);
    k7a_mfma<<<dim3(HW_ / 256, NH_), 256, 0, stream>>>(z, attn, att_out);
    k7b_mfma<<<THW_ / 256, 256, 0, stream>>>(att_out, Wout, out_b);
  }
}

// Round 7
// 333.378 us; speedup vs baseline: 1.2522x; 1.2522x over previous
//
#include <hip/hip_runtime.h>
#include <hip/hip_bf16.h>

#define C_  64
#define C3_ 192
#define T_  10
#define H_  128
#define W_  128
#define HW_ 16384        // H_*W_
#define THW_ 163840      // T_*HW_
#define NH_ 8
#define C2_ 24
#define TG_ 80           // t * SHUFFLE_G

typedef __hip_bfloat16 bf16;
typedef __attribute__((ext_vector_type(8))) short bf16x8;
typedef __attribute__((ext_vector_type(4))) float f32x4;

__device__ __forceinline__ float bf2f(bf16 v) { return __bfloat162float(v); }

__device__ __forceinline__ ushort f2bf_s(float f) {
  bf16 h = __float2bfloat16(f);
  union { bf16 b; ushort s; } u; u.b = h; return u.s;
}

__device__ __forceinline__ void unpack8(uint4 u, float* f) {
  f[0] = __uint_as_float(u.x << 16); f[1] = __uint_as_float(u.x & 0xffff0000u);
  f[2] = __uint_as_float(u.y << 16); f[3] = __uint_as_float(u.y & 0xffff0000u);
  f[4] = __uint_as_float(u.z << 16); f[5] = __uint_as_float(u.z & 0xffff0000u);
  f[6] = __uint_as_float(u.w << 16); f[7] = __uint_as_float(u.w & 0xffff0000u);
}

__device__ __forceinline__ ushort4 pack4(f32x4 a) {
  ushort4 p;
  p.x = f2bf_s(a[0]); p.y = f2bf_s(a[1]); p.z = f2bf_s(a[2]); p.w = f2bf_s(a[3]);
  return p;
}

// ================ K1 (MFMA): y1 = W1 @ x, global_load_lds f32 staging ================
// LDS: x[64][260] f32 row-major; each row = one 64-lane x 16B DMA (1 KB).
#define XS_STRIDE 260
__global__ __launch_bounds__(256) void k1_mfma(
    const float* __restrict__ x, const float* __restrict__ W1,
    bf16* __restrict__ y1) {
  __shared__ __align__(16) float xs[64 * XS_STRIDE];   // 66,560 B
  const int tid = threadIdx.x;
  const int n0 = blockIdx.x * 256;
  const int mh = blockIdx.y;
  const int lane = tid & 63, wv = tid >> 6;
  const int lr = lane & 15, lg = lane >> 4;

  // ---- DMA stage: wave wv stages rows wv*16 .. wv*16+15 ----
  {
    const int l4 = lane * 4;
#pragma unroll
    for (int it = 0; it < 16; ++it) {
      const int row = wv * 16 + it;
      const float* gsrc = x + (size_t)row * THW_ + n0 + l4;
      __builtin_amdgcn_global_load_lds(
          (const __attribute__((address_space(1))) void*)gsrc,
          (__attribute__((address_space(3))) void*)&xs[row * XS_STRIDE],
          16, 0, 0);
    }
  }

  // ---- W fragments (overlap the DMA) ----
  bf16x8 wf[6][2];
#pragma unroll
  for (int mt = 0; mt < 6; ++mt)
#pragma unroll
    for (int c = 0; c < 2; ++c) {
      const int row = mh * 96 + mt * 16 + lr;
      const int k0 = c * 32 + lg * 8;
      const float* wp = W1 + row * 64 + k0;
      float4 a0 = *reinterpret_cast<const float4*>(wp);
      float4 a1 = *reinterpret_cast<const float4*>(wp + 4);
      bf16x8 f;
      f[0]=f2bf_s(a0.x); f[1]=f2bf_s(a0.y); f[2]=f2bf_s(a0.z); f[3]=f2bf_s(a0.w);
      f[4]=f2bf_s(a1.x); f[5]=f2bf_s(a1.y); f[6]=f2bf_s(a1.z); f[7]=f2bf_s(a1.w);
      wf[mt][c] = f;
    }
  __syncthreads();   // drains the DMA (vmcnt 0) + barrier

#pragma unroll
  for (int nt = 0; nt < 4; ++nt) {
    const int col = wv * 64 + nt * 16 + lr;
    bf16x8 xa[2];
#pragma unroll
    for (int c = 0; c < 2; ++c) {
      const float* base = &xs[(c * 32 + lg * 8) * XS_STRIDE + col];
      bf16x8 f;
#pragma unroll
      for (int e = 0; e < 8; ++e) f[e] = f2bf_s(base[e * XS_STRIDE]);
      xa[c] = f;
    }
    f32x4 acc[6];
#pragma unroll
    for (int mt = 0; mt < 6; ++mt) acc[mt] = (f32x4){0.f, 0.f, 0.f, 0.f};
#pragma unroll
    for (int c = 0; c < 2; ++c)
#pragma unroll
      for (int mt = 0; mt < 6; ++mt)
        acc[mt] = __builtin_amdgcn_mfma_f32_16x16x32_bf16(xa[c], wf[mt][c], acc[mt], 0, 0, 0);
    const int nb = n0 + wv * 64 + nt * 16 + lg * 4;
#pragma unroll
    for (int mt = 0; mt < 6; ++mt) {
      const int o = mh * 96 + mt * 16 + lr;
      *reinterpret_cast<ushort4*>(y1 + (size_t)o * THW_ + nb) = pack4(acc[mt]);
    }
  }
}

// ================ K2: depthwise 3x3, 32x128 tile, conflict-free ================
__global__ __launch_bounds__(256) void k2_dw(
    const bf16* __restrict__ y1, const float* __restrict__ Wdw,
    bf16* __restrict__ y2) {
  __shared__ float tile[34][132];
  const int tid = threadIdx.x;
  const int blk = blockIdx.x;
  const int hs = (blk & 3) * 32;
  const int rest = blk >> 2;
  const int t = rest % T_;
  const int o = rest / T_;
  const bf16* src = y1 + ((size_t)o * T_ + t) * HW_;

  if (tid < 68) {
    const int r = tid >> 1, side = tid & 1;
    tile[r][side ? 129 : 0] = 0.f;
  }
  {
    const int rr = tid >> 5, c4 = (tid & 31) * 4;
#pragma unroll
    for (int p = 0; p < 5; ++p) {
      const int r = p * 8 + rr;
      if (r < 34) {
        const int hh = hs - 1 + r;
        float e0 = 0.f, e1 = 0.f, e2 = 0.f, e3 = 0.f;
        if (hh >= 0 && hh < H_) {
          uint2 raw = *reinterpret_cast<const uint2*>(src + hh * W_ + c4);
          e0 = __uint_as_float(raw.x << 16);
          e1 = __uint_as_float(raw.x & 0xffff0000u);
          e2 = __uint_as_float(raw.y << 16);
          e3 = __uint_as_float(raw.y & 0xffff0000u);
        }
        tile[r][1 + c4]     = e0;
        tile[r][1 + c4 + 1] = e1;
        tile[r][1 + c4 + 2] = e2;
        tile[r][1 + c4 + 3] = e3;
      }
    }
  }
  __syncthreads();

  float kk[9];
#pragma unroll
  for (int i = 0; i < 9; ++i) kk[i] = Wdw[o * 9 + i];

  bf16* dst = y2 + ((size_t)o * T_ + t) * HW_;
  const int w = tid & 127;
  const int r0 = (tid >> 7) * 16;

  float a[3][3];
#pragma unroll
  for (int ky = 0; ky < 3; ++ky)
#pragma unroll
    for (int kx = 0; kx < 3; ++kx) a[ky][kx] = tile[r0 + ky][w + kx];

#pragma unroll
  for (int q = 0; q < 16; ++q) {
    float acc = 0.f;
#pragma unroll
    for (int ky = 0; ky < 3; ++ky)
#pragma unroll
      for (int kx = 0; kx < 3; ++kx)
        acc = fmaf(kk[ky * 3 + kx], a[ky][kx], acc);
    dst[(hs + r0 + q) * W_ + w] = __float2bfloat16(acc);
    if (q < 15) {
#pragma unroll
      for (int kx = 0; kx < 3; ++kx) {
        a[0][kx] = a[1][kx];
        a[1][kx] = a[2][kx];
        a[2][kx] = tile[r0 + q + 3][w + kx];
      }
    }
  }
}

// ================ K3 (MFMA, staged LDS): z = W_lin @ shuffled(y2) + b ================
#define K3_NKC 14
#define K3_STRIDE 224
__global__ __launch_bounds__(256) void k3_mfma(
    const bf16* __restrict__ y2, const float* __restrict__ W_lin,
    const float* __restrict__ b_lin, bf16* __restrict__ z) {
  __shared__ __align__(16) char lds[256 * K3_STRIDE];   // 56 KiB
  const int tid = threadIdx.x;
  const int s0 = blockIdx.x * 256;
  const int c2 = blockIdx.y;

  {
    const int cg = tid >> 3, dk = tid & 7;
    for (int it = 0; it < 10; ++it) {
      const int k = it * 8 + dk;
      const int c1 = (k * 205) >> 11;
      const int tt = k - c1 * 10;
      const bf16* src = y2 + ((size_t)((c1 * C2_ + c2) * T_ + tt)) * HW_ + s0 + cg * 8;
      uint4 raw = *reinterpret_cast<const uint4*>(src);
      const ushort* v = reinterpret_cast<const ushort*>(&raw);
      const int kc = k >> 3, ke = k & 7;
      int r = (kc + cg * 8) % K3_NKC;
#pragma unroll
      for (int j = 0; j < 8; ++j) {
        const int col = cg * 8 + j;
        *reinterpret_cast<ushort*>(lds + col * K3_STRIDE + r * 16 + ke * 2) = v[j];
        r = (r + 1 == K3_NKC) ? 0 : r + 1;
      }
    }
    const int col = tid;
    const uint4 zero4 = {0, 0, 0, 0};
    *reinterpret_cast<uint4*>(lds + col * K3_STRIDE + ((10 + col) % K3_NKC) * 16) = zero4;
    *reinterpret_cast<uint4*>(lds + col * K3_STRIDE + ((11 + col) % K3_NKC) * 16) = zero4;
  }
  __syncthreads();

  const int lane = tid & 63, wv = tid >> 6;
  const int lr = lane & 15, lg = lane >> 4;

  bf16x8 wf[5][3];
#pragma unroll
  for (int mt = 0; mt < 5; ++mt)
#pragma unroll
    for (int c = 0; c < 3; ++c) {
      const int row = mt * 16 + lr;
      const int k0 = c * 32 + lg * 8;
      bf16x8 f;
      if (k0 < 80) {
        const float* wp = W_lin + row * 80 + k0;
        float4 a0 = *reinterpret_cast<const float4*>(wp);
        float4 a1 = *reinterpret_cast<const float4*>(wp + 4);
        f[0]=f2bf_s(a0.x); f[1]=f2bf_s(a0.y); f[2]=f2bf_s(a0.z); f[3]=f2bf_s(a0.w);
        f[4]=f2bf_s(a1.x); f[5]=f2bf_s(a1.y); f[6]=f2bf_s(a1.z); f[7]=f2bf_s(a1.w);
      } else {
        f = (bf16x8){0,0,0,0,0,0,0,0};
      }
      wf[mt][c] = f;
    }
  float bias[5];
#pragma unroll
  for (int mt = 0; mt < 5; ++mt) bias[mt] = b_lin[mt * 16 + lr];

  for (int nt = 0; nt < 4; ++nt) {
    const int col = wv * 64 + nt * 16 + lr;
    bf16x8 xa[3];
#pragma unroll
    for (int c = 0; c < 3; ++c) {
      const int kc = c * 4 + lg;
      xa[c] = *reinterpret_cast<const bf16x8*>(
          lds + col * K3_STRIDE + ((kc + col) % K3_NKC) * 16);
    }
    f32x4 acc[5];
#pragma unroll
    for (int mt = 0; mt < 5; ++mt)
      acc[mt] = (f32x4){bias[mt], bias[mt], bias[mt], bias[mt]};
#pragma unroll
    for (int c = 0; c < 3; ++c)
#pragma unroll
      for (int mt = 0; mt < 5; ++mt)
        acc[mt] = __builtin_amdgcn_mfma_f32_16x16x32_bf16(xa[c], wf[mt][c], acc[mt], 0, 0, 0);
    const int sb = s0 + wv * 64 + nt * 16 + lg * 4;
#pragma unroll
    for (int mt = 0; mt < 5; ++mt) {
      const int u = c2 * TG_ + mt * 16 + lr;
      *reinterpret_cast<ushort4*>(z + (size_t)u * HW_ + sb) = pack4(acc[mt]);
    }
  }
}

// ================ K4: sum of squares for q,k rows — unchanged ================
__global__ __launch_bounds__(256) void k4_ssq(
    const bf16* __restrict__ z, float* __restrict__ ssq) {
  __shared__ float red[256];
  int u = blockIdx.x;
  const bf16* p = z + (size_t)u * HW_;
  float acc = 0.f;
  for (int it = 0; it < 8; ++it) {
    int s = it * 2048 + threadIdx.x * 8;
    uint4 raw = *reinterpret_cast<const uint4*>(p + s);
    float f[8]; unpack8(raw, f);
#pragma unroll
    for (int e = 0; e < 8; ++e) acc = fmaf(f[e], f[e], acc);
  }
  red[threadIdx.x] = acc;
  __syncthreads();
  for (int st = 128; st > 0; st >>= 1) {
    if (threadIdx.x < st) red[threadIdx.x] += red[threadIdx.x + st];
    __syncthreads();
  }
  if (threadIdx.x == 0) ssq[u] = red[0];
}

// ================ K5 (MFMA): Gpart[chunk] = partial QK^T over 512-s chunk — unchanged ================
__global__ __launch_bounds__(256) void k5_mfma(
    const bf16* __restrict__ z, float* __restrict__ Gpart) {
  __shared__ __align__(16) float gbuf[2][TG_ * TG_];   // 51.2 KiB
  const int chunk = blockIdx.x, h = blockIdx.y;
  const int tid = threadIdx.x;
  const int lane = tid & 63, wv = tid >> 6;
  const int lr = lane & 15, lg = lane >> 4;

  const bf16* qbase = z + (size_t)(h * TG_) * HW_;
  const bf16* kbase = z + (size_t)((8 + h) * TG_) * HW_;

  f32x4 acc[5][5];
#pragma unroll
  for (int a = 0; a < 5; ++a)
#pragma unroll
    for (int b2 = 0; b2 < 5; ++b2) acc[a][b2] = (f32x4){0.f, 0.f, 0.f, 0.f};

  const int s0 = chunk * 512 + wv * 128;
  for (int s = s0; s < s0 + 128; s += 32) {
    bf16x8 qa[5], kb[5];
#pragma unroll
    for (int a = 0; a < 5; ++a)
      qa[a] = *reinterpret_cast<const bf16x8*>(qbase + (size_t)(a * 16 + lr) * HW_ + s + lg * 8);
#pragma unroll
    for (int a = 0; a < 5; ++a)
      kb[a] = *reinterpret_cast<const bf16x8*>(kbase + (size_t)(a * 16 + lr) * HW_ + s + lg * 8);
#pragma unroll
    for (int a = 0; a < 5; ++a)
#pragma unroll
      for (int b2 = 0; b2 < 5; ++b2)
        acc[a][b2] = __builtin_amdgcn_mfma_f32_16x16x32_bf16(qa[a], kb[b2], acc[a][b2], 0, 0, 0);
  }

  if (wv == 1 || wv == 3) {
    float* dst = gbuf[wv >> 1];
#pragma unroll
    for (int a = 0; a < 5; ++a)
#pragma unroll
      for (int b2 = 0; b2 < 5; ++b2)
#pragma unroll
        for (int j = 0; j < 4; ++j)
          dst[(a * 16 + lg * 4 + j) * TG_ + b2 * 16 + lr] = acc[a][b2][j];
  }
  __syncthreads();
  if (wv == 0 || wv == 2) {
    const float* srcb = gbuf[wv >> 1];
#pragma unroll
    for (int a = 0; a < 5; ++a)
#pragma unroll
      for (int b2 = 0; b2 < 5; ++b2)
#pragma unroll
        for (int j = 0; j < 4; ++j)
          acc[a][b2][j] += srcb[(a * 16 + lg * 4 + j) * TG_ + b2 * 16 + lr];
  }
  __syncthreads();
  if (wv == 2) {
#pragma unroll
    for (int a = 0; a < 5; ++a)
#pragma unroll
      for (int b2 = 0; b2 < 5; ++b2)
#pragma unroll
        for (int j = 0; j < 4; ++j)
          gbuf[0][(a * 16 + lg * 4 + j) * TG_ + b2 * 16 + lr] = acc[a][b2][j];
  }
  __syncthreads();
  if (wv == 0) {
    float* gp = Gpart + ((size_t)chunk * 8 + h) * TG_ * TG_;
#pragma unroll
    for (int a = 0; a < 5; ++a)
#pragma unroll
      for (int b2 = 0; b2 < 5; ++b2)
#pragma unroll
        for (int j = 0; j < 4; ++j) {
          const int i = a * 16 + lg * 4 + j, jj = b2 * 16 + lr;
          gp[i * TG_ + jj] = acc[a][b2][j] + gbuf[0][i * TG_ + jj];
        }
  }
}

// ================ K6: softmax — unchanged ================
__global__ __launch_bounds__(128) void k6_softmax(
    const float* __restrict__ Gpart, const float* __restrict__ ssq,
    const float* __restrict__ temp, float* __restrict__ attn) {
  __shared__ float red[128];
  __shared__ float smax, ssum;
  int h = blockIdx.x / TG_, i = blockIdx.x % TG_;
  int j = threadIdx.x;
  float logit = -1e30f;
  if (j < TG_) {
    float g = 0.f;
    for (int c = 0; c < 32; ++c)
      g += Gpart[(((size_t)c * 8 + h) * TG_ + i) * TG_ + j];
    float nq = ssq[h * TG_ + i];
    float nk = ssq[(8 + h) * TG_ + j];
    float sq = 1.f / fmaxf(sqrtf(nq), 1e-12f);
    float sk = 1.f / fmaxf(sqrtf(nk), 1e-12f);
    logit = g * sq * sk * temp[h];
  }
  red[j] = logit;
  __syncthreads();
  if (j == 0) {
    float m = -1e30f;
    for (int x2 = 0; x2 < TG_; ++x2) m = fmaxf(m, red[x2]);
    smax = m;
  }
  __syncthreads();
  float e = (j < TG_) ? expf(logit - smax) : 0.f;
  red[j] = e;
  __syncthreads();
  if (j == 0) {
    float s = 0.f;
    for (int x2 = 0; x2 < TG_; ++x2) s += red[x2];
    ssum = s;
  }
  __syncthreads();
  if (j < TG_) attn[((size_t)h * TG_ + i) * TG_ + j] = e / ssum;
}

// ================ K7a (MFMA, staged LDS): att_out = attn @ v ================
__global__ __launch_bounds__(256) void k7a_mfma(
    const bf16* __restrict__ z, const float* __restrict__ attn,
    bf16* __restrict__ att_out) {
  __shared__ __align__(16) char lds[256 * K3_STRIDE];   // 56 KiB
  const int tid = threadIdx.x;
  const int s0 = blockIdx.x * 256;
  const int h = blockIdx.y;
  const int voff = (16 + h) * TG_;

  {
    const int cg = tid >> 3, dk = tid & 7;
    for (int it = 0; it < 10; ++it) {
      const int k = it * 8 + dk;
      const bf16* src = z + (size_t)(voff + k) * HW_ + s0 + cg * 8;
      uint4 raw = *reinterpret_cast<const uint4*>(src);
      const ushort* v = reinterpret_cast<const ushort*>(&raw);
      const int kc = k >> 3, ke = k & 7;
      int r = (kc + cg * 8) % K3_NKC;
#pragma unroll
      for (int j = 0; j < 8; ++j) {
        const int col = cg * 8 + j;
        *reinterpret_cast<ushort*>(lds + col * K3_STRIDE + r * 16 + ke * 2) = v[j];
        r = (r + 1 == K3_NKC) ? 0 : r + 1;
      }
    }
    const int col = tid;
    const uint4 zero4 = {0, 0, 0, 0};
    *reinterpret_cast<uint4*>(lds + col * K3_STRIDE + ((10 + col) % K3_NKC) * 16) = zero4;
    *reinterpret_cast<uint4*>(lds + col * K3_STRIDE + ((11 + col) % K3_NKC) * 16) = zero4;
  }
  __syncthreads();

  const int lane = tid & 63, wv = tid >> 6;
  const int lr = lane & 15, lg = lane >> 4;

  bf16x8 wf[5][3];
#pragma unroll
  for (int mt = 0; mt < 5; ++mt)
#pragma unroll
    for (int c = 0; c < 3; ++c) {
      const int row = mt * 16 + lr;
      const int k0 = c * 32 + lg * 8;
      bf16x8 f;
      if (k0 < 80) {
        const float* ap = attn + ((size_t)h * TG_ + row) * TG_ + k0;
        float4 a0 = *reinterpret_cast<const float4*>(ap);
        float4 a1 = *reinterpret_cast<const float4*>(ap + 4);
        f[0]=f2bf_s(a0.x); f[1]=f2bf_s(a0.y); f[2]=f2bf_s(a0.z); f[3]=f2bf_s(a0.w);
        f[4]=f2bf_s(a1.x); f[5]=f2bf_s(a1.y); f[6]=f2bf_s(a1.z); f[7]=f2bf_s(a1.w);
      } else {
        f = (bf16x8){0,0,0,0,0,0,0,0};
      }
      wf[mt][c] = f;
    }

  for (int nt = 0; nt < 4; ++nt) {
    const int col = wv * 64 + nt * 16 + lr;
    bf16x8 xa[3];
#pragma unroll
    for (int c = 0; c < 3; ++c) {
      const int kc = c * 4 + lg;
      xa[c] = *reinterpret_cast<const bf16x8*>(
          lds + col * K3_STRIDE + ((kc + col) % K3_NKC) * 16);
    }
    f32x4 acc[5];
#pragma unroll
    for (int mt = 0; mt < 5; ++mt) acc[mt] = (f32x4){0.f, 0.f, 0.f, 0.f};
#pragma unroll
    for (int c = 0; c < 3; ++c)
#pragma unroll
      for (int mt = 0; mt < 5; ++mt)
        acc[mt] = __builtin_amdgcn_mfma_f32_16x16x32_bf16(xa[c], wf[mt][c], acc[mt], 0, 0, 0);
    const int sb = s0 + wv * 64 + nt * 16 + lg * 4;
#pragma unroll
    for (int mt = 0; mt < 5; ++mt) {
      const int u = h * TG_ + mt * 16 + lr;
      *reinterpret_cast<ushort4*>(att_out + (size_t)u * HW_ + sb) = pack4(acc[mt]);
    }
  }
}

// ================ K7b (MFMA, staged LDS): out = W_out @ regroup(att_out), f32 out ================
#define K1_NKC 10
#define K1_STRIDE 160
__global__ __launch_bounds__(256) void k7b_mfma(
    const bf16* __restrict__ att_out, const float* __restrict__ W_out,
    float* __restrict__ out) {
  __shared__ __align__(16) char lds[256 * K1_STRIDE];   // 40 KiB
  const int tid = threadIdx.x;
  const int n0 = blockIdx.x * 256;
  const int t = n0 >> 14;
  const int sb0 = n0 & (HW_ - 1);

  {
    const int cg = tid >> 3, dk = tid & 7;
    for (int it = 0; it < 8; ++it) {
      const int k = it * 8 + dk;
      const int row = (k >> 3) * TG_ + (k & 7) * T_ + t;
      const bf16* src = att_out + (size_t)row * HW_ + sb0 + cg * 8;
      uint4 raw = *reinterpret_cast<const uint4*>(src);
      const ushort* v = reinterpret_cast<const ushort*>(&raw);
      int r = (it + cg * 8) % K1_NKC;
#pragma unroll
      for (int j = 0; j < 8; ++j) {
        const int col = cg * 8 + j;
        *reinterpret_cast<ushort*>(lds + col * K1_STRIDE + r * 16 + dk * 2) = v[j];
        r = (r + 1 == K1_NKC) ? 0 : r + 1;
      }
    }
  }
  __syncthreads();

  const int lane = tid & 63, wv = tid >> 6;
  const int lr = lane & 15, lg = lane >> 4;

  bf16x8 wf[4][2];
#pragma unroll
  for (int mt = 0; mt < 4; ++mt)
#pragma unroll
    for (int c = 0; c < 2; ++c) {
      const int row = mt * 16 + lr;
      const int k0 = c * 32 + lg * 8;
      const float* wp = W_out + row * 64 + k0;
      float4 a0 = *reinterpret_cast<const float4*>(wp);
      float4 a1 = *reinterpret_cast<const float4*>(wp + 4);
      bf16x8 f;
      f[0]=f2bf_s(a0.x); f[1]=f2bf_s(a0.y); f[2]=f2bf_s(a0.z); f[3]=f2bf_s(a0.w);
      f[4]=f2bf_s(a1.x); f[5]=f2bf_s(a1.y); f[6]=f2bf_s(a1.z); f[7]=f2bf_s(a1.w);
      wf[mt][c] = f;
    }

  for (int nt = 0; nt < 4; ++nt) {
    const int col = wv * 64 + nt * 16 + lr;
    bf16x8 xa[2];
#pragma unroll
    for (int c = 0; c < 2; ++c) {
      const int kc = c * 4 + lg;
      xa[c] = *reinterpret_cast<const bf16x8*>(
          lds + col * K1_STRIDE + ((kc + col) % K1_NKC) * 16);
    }
    f32x4 acc[4];
#pragma unroll
    for (int mt = 0; mt < 4; ++mt) acc[mt] = (f32x4){0.f, 0.f, 0.f, 0.f};
#pragma unroll
    for (int c = 0; c < 2; ++c)
#pragma unroll
      for (int mt = 0; mt < 4; ++mt)
        acc[mt] = __builtin_amdgcn_mfma_f32_16x16x32_bf16(xa[c], wf[mt][c], acc[mt], 0, 0, 0);
    const int nb = n0 + wv * 64 + nt * 16 + lg * 4;
#pragma unroll
    for (int mt = 0; mt < 4; ++mt) {
      const int o = mt * 16 + lr;
      *reinterpret_cast<float4*>(out + (size_t)o * THW_ + nb) =
          (float4){acc[mt][0], acc[mt][1], acc[mt][2], acc[mt][3]};
    }
  }
}

extern "C" void kernel_launch(void* const* d_in, const int* in_sizes, int n_in,
                              void* d_out, int out_size, void* d_ws, size_t ws_size,
                              hipStream_t stream) {
  const float* x    = (const float*)d_in[0];
  const float* W1   = (const float*)d_in[1];
  const float* Wdw  = (const float*)d_in[2];
  const float* Wlin = (const float*)d_in[3];
  const float* blin = (const float*)d_in[4];
  const float* temp = (const float*)d_in[5];
  const float* Wout = (const float*)d_in[6];
  float* out = (float*)d_out;

  const size_t SLOT = (size_t)C3_ * THW_ * 2;   // 62,914,560 bytes
  char* ws = (char*)d_ws;
  bf16* slotA = (bf16*)ws;
  char* slotB = ws + SLOT;

  bf16* y1 = slotA;
  bf16* y2 = (bf16*)slotB;
  bf16* z  = slotA;
  float* Gpart   = (float*)slotB;                // 6,553,600 B
  float* attn    = (float*)(slotB + 6553600);    //   204,800 B
  float* ssq     = (float*)(slotB + 6758400);    //     5,120 B
  bf16*  att_out = (bf16*)(slotB + 6763520);     // 20,971,520 B

  for (int b = 0; b < 2; ++b) {
    const float* x_b = x + (size_t)b * C_ * THW_;
    float* out_b = out + (size_t)b * C_ * THW_;

    k1_mfma<<<dim3(THW_ / 256, 2), 256, 0, stream>>>(x_b, W1, y1);
    k2_dw<<<C3_ * T_ * 4, 256, 0, stream>>>(y1, Wdw, y2);
    k3_mfma<<<dim3(HW_ / 256, C2_), 256, 0, stream>>>(y2, Wlin, blin, z);
    k4_ssq<<<1280, 256, 0, stream>>>(z, ssq);
    k5_mfma<<<dim3(32, NH_), 256, 0, stream>>>(z, Gpart);
    k6_softmax<<<8 * TG_, 128, 0, stream>>>(Gpart, ssq, temp, attn);
    k7a_mfma<<<dim3(HW_ / 256, NH_), 256, 0, stream>>>(z, attn, att_out);
    k7b_mfma<<<THW_ / 256, 256, 0, stream>>>(att_out, Wout, out_b);
  }
}